// Round 12
// baseline (300.542 us; speedup 1.0000x reference)
//
#include <hip/hip_runtime.h>
#include <hip/hip_bf16.h>
#include <stdint.h>

typedef __attribute__((ext_vector_type(8))) short bf16x8;
typedef __attribute__((ext_vector_type(4))) float f32x4;
typedef __attribute__((ext_vector_type(8))) unsigned short ushort8;

__device__ __forceinline__ float bf2f(unsigned short u) {
  union { unsigned int i; float f; } x; x.i = ((unsigned int)u) << 16; return x.f;
}
__device__ __forceinline__ unsigned short f2bf(float f) {
  union { __hip_bfloat16 h; unsigned short u; } x; x.h = __float2bfloat16(f); return x.u;
}

__device__ __forceinline__ void gload_lds16(const void* g, void* l) {
  __builtin_amdgcn_global_load_lds((__attribute__((address_space(1))) const void*)g,
                                   (__attribute__((address_space(3))) void*)l, 16, 0, 0);
}

// ---------------- f32 -> bf16 convert, 3 tensors batched on z ----------------
__global__ __launch_bounds__(256) void cvt3_kernel(const float* __restrict__ a,
                                                   const float* __restrict__ b,
                                                   const float* __restrict__ c,
                                                   unsigned short* __restrict__ oa,
                                                   unsigned short* __restrict__ ob,
                                                   unsigned short* __restrict__ oc,
                                                   int n8) {
  const float* in = blockIdx.y == 0 ? a : blockIdx.y == 1 ? b : c;
  unsigned short* out = blockIdx.y == 0 ? oa : blockIdx.y == 1 ? ob : oc;
  int i = blockIdx.x * 256 + threadIdx.x;
  if (i >= n8) return;
  const float4* p = (const float4*)(in + (size_t)i * 8);
  float4 x = p[0], y = p[1];
  ushort8 o;
  o[0] = f2bf(x.x); o[1] = f2bf(x.y); o[2] = f2bf(x.z); o[3] = f2bf(x.w);
  o[4] = f2bf(y.x); o[5] = f2bf(y.y); o[6] = f2bf(y.z); o[7] = f2bf(y.w);
  *(ushort8*)(out + (size_t)i * 8) = o;
}

// ======================================================================
// Shared 4-phase 256x256 GEMM K-loop (r11-verified). acc[8][4] +=
// A[256,1024] @ B[256,1024]^T tile at (bm,bn). Counted vmcnt(4) at P2/P4.
// Swizzle (0-conflict): phys granule = logical ^ ((row>>1)&3), both sides.
// ======================================================================
__device__ __forceinline__ void gemm256_loop(
    const unsigned short* __restrict__ A,
    const unsigned short* __restrict__ B,
    int bm, int bn,
    unsigned short (*As)[256][32], unsigned short (*Bs)[256][32],
    f32x4 (*acc)[4]) {
  const int tid = threadIdx.x;
  const int widx = tid >> 6, lane = tid & 63;
  const int wr = widx >> 2, wc = widx & 3;
  const int fr = lane & 15, fkg = lane >> 4;
  const int pgo = (fkg ^ ((fr >> 1) & 3)) * 8;          // swizzled read granule
  const int srow = lane >> 2;                           // staging row-in-16
  const int sg = ((lane & 3) ^ ((lane >> 3) & 3)) * 8;  // swizzled source granule

  const size_t abase = (size_t)(bm * 256) * 1024;
  const size_t bbase = (size_t)(bn * 256) * 1024;

  bf16x8 aF[8], bF[4];

#define STG_A(bufi, kh, kt)                                                                \
  {                                                                                        \
    gload_lds16(A + abase + (size_t)(widx * 16 + srow) * 1024 + (kt) * 64 + (kh) * 32 + sg,\
                &As[(bufi) * 2 + (kh)][widx * 16][0]);                                     \
    gload_lds16(A + abase + (size_t)(128 + widx * 16 + srow) * 1024 + (kt) * 64 + (kh) * 32 + sg, \
                &As[(bufi) * 2 + (kh)][128 + widx * 16][0]);                               \
  }
#define STG_B(bufi, kh, kt)                                                                \
  {                                                                                        \
    gload_lds16(B + bbase + (size_t)(widx * 16 + srow) * 1024 + (kt) * 64 + (kh) * 32 + sg,\
                &Bs[(bufi) * 2 + (kh)][widx * 16][0]);                                     \
    gload_lds16(B + bbase + (size_t)(128 + widx * 16 + srow) * 1024 + (kt) * 64 + (kh) * 32 + sg, \
                &Bs[(bufi) * 2 + (kh)][128 + widx * 16][0]);                               \
  }
#define LDA(bufi, ks)                                                                      \
  _Pragma("unroll") for (int m = 0; m < 8; ++m)                                            \
      aF[m] = *(const bf16x8*)&As[(bufi) * 2 + (ks)][wr * 128 + m * 16 + fr][pgo];
#define LDBALL(bufi, ks)                                                                   \
  _Pragma("unroll") for (int n = 0; n < 4; ++n)                                            \
      bF[n] = *(const bf16x8*)&Bs[(bufi) * 2 + (ks)][wc * 64 + n * 16 + fr][pgo];
#define MMALL()                                                                            \
  {                                                                                        \
    __builtin_amdgcn_s_setprio(1);                                                         \
    _Pragma("unroll") for (int m = 0; m < 8; ++m)                                          \
        _Pragma("unroll") for (int n = 0; n < 4; ++n)                                      \
            acc[m][n] = __builtin_amdgcn_mfma_f32_16x16x32_bf16(aF[m], bF[n], acc[m][n], 0, 0, 0); \
    __builtin_amdgcn_s_setprio(0);                                                         \
  }
#define BARM() asm volatile("s_barrier" ::: "memory")
#define VMW(N) asm volatile("s_waitcnt vmcnt(" #N ")" ::: "memory")

  STG_A(0, 0, 0); STG_B(0, 0, 0);
  STG_A(0, 1, 0); STG_B(0, 1, 0);
  STG_A(1, 0, 1); STG_B(1, 0, 1);
  VMW(4);
  BARM();

  for (int i = 0; i < 8; ++i) {
    const int t1s = 2 * i + 1, u0 = 2 * i + 2, u1 = 2 * i + 3;
    const bool st = (i < 7);
    LDA(0, 0); LDBALL(0, 0); STG_A(1, 1, t1s); STG_B(1, 1, t1s);
    BARM(); MMALL(); BARM();
    LDA(0, 1); LDBALL(0, 1); if (st) { STG_A(0, 0, u0); STG_B(0, 0, u0); }
    BARM(); MMALL();
    if (st) { VMW(4); } else { VMW(0); }
    BARM();
    LDA(1, 0); LDBALL(1, 0); if (st) { STG_A(0, 1, u0); STG_B(0, 1, u0); }
    BARM(); MMALL(); BARM();
    LDA(1, 1); LDBALL(1, 1); if (st) { STG_A(1, 0, u1); STG_B(1, 0, u1); }
    BARM(); MMALL();
    if (st) { VMW(4); } else { VMW(0); }
    BARM();
  }
#undef STG_A
#undef STG_B
#undef LDA
#undef LDBALL
#undef MMALL
#undef BARM
#undef VMW
}

// ======================================================================
// projkv: per block (bm,bn): kh = norm(k@Wk^T+bk) (held in regs),
// vh = norm(v@Wv^T+bv), then kv partial for the 4 heads of bn over this
// block's 256 rows via LDS-transposed tiles (reusing the dead As/Bs 128KB).
// kh/vh are NEVER written to HBM. kvp[chunk=bm&15][bh][64][64] f32.
// ======================================================================
__global__ __launch_bounds__(512, 1) void projkv_kernel(
    const unsigned short* __restrict__ kbf,
    const unsigned short* __restrict__ vbf,
    const unsigned short* __restrict__ Wkb,
    const unsigned short* __restrict__ Wvb,
    const float* __restrict__ bkb,
    const float* __restrict__ bvb,
    float* __restrict__ kvp) {
  __shared__ unsigned short As[4][256][32];
  __shared__ unsigned short Bs[4][256][32];
  const int flat = blockIdx.y * 4 + blockIdx.x;  // 256, %8==0
  const int swz = (flat & 7) * 32 + (flat >> 3); // bijective
  const int bm = swz >> 2, bn = swz & 3;

  const int tid = threadIdx.x, widx = tid >> 6, lane = tid & 63;
  const int wr = widx >> 2, wc = widx & 3;
  const int fr = lane & 15, fkg = lane >> 4, g4 = fkg * 4;

  f32x4 acc[8][4];
  unsigned short khp[8][4][4], vhp[8][4][4];

  // ---- K projection + norm -> khp regs ----
#pragma unroll
  for (int m = 0; m < 8; ++m)
#pragma unroll
    for (int n = 0; n < 4; ++n) acc[m][n] = (f32x4){0.f, 0.f, 0.f, 0.f};
  gemm256_loop(kbf, Wkb, bm, bn, As, Bs, acc);
  {
    float bsv[4];
#pragma unroll
    for (int n = 0; n < 4; ++n) bsv[n] = bkb[bn * 256 + wc * 64 + n * 16 + fr];
#pragma unroll
    for (int m = 0; m < 8; ++m) {
      float val[4][4], inv[4];
#pragma unroll
      for (int j = 0; j < 4; ++j) {
        float s = 0.f;
#pragma unroll
        for (int n = 0; n < 4; ++n) {
          val[n][j] = acc[m][n][j] + bsv[n];
          s += val[n][j] * val[n][j];
        }
        s += __shfl_xor(s, 1); s += __shfl_xor(s, 2);
        s += __shfl_xor(s, 4); s += __shfl_xor(s, 8);
        inv[j] = 1.f / fmaxf(sqrtf(s), 1e-12f);
      }
#pragma unroll
      for (int n = 0; n < 4; ++n)
#pragma unroll
        for (int j = 0; j < 4; ++j) khp[m][n][j] = f2bf(val[n][j] * inv[j]);
    }
  }

  // ---- V projection + norm -> vhp regs ----
#pragma unroll
  for (int m = 0; m < 8; ++m)
#pragma unroll
    for (int n = 0; n < 4; ++n) acc[m][n] = (f32x4){0.f, 0.f, 0.f, 0.f};
  gemm256_loop(vbf, Wvb, bm, bn, As, Bs, acc);
  {
    float bsv[4];
#pragma unroll
    for (int n = 0; n < 4; ++n) bsv[n] = bvb[bn * 256 + wc * 64 + n * 16 + fr];
#pragma unroll
    for (int m = 0; m < 8; ++m) {
      float val[4][4], inv[4];
#pragma unroll
      for (int j = 0; j < 4; ++j) {
        float s = 0.f;
#pragma unroll
        for (int n = 0; n < 4; ++n) {
          val[n][j] = acc[m][n][j] + bsv[n];
          s += val[n][j] * val[n][j];
        }
        s += __shfl_xor(s, 1); s += __shfl_xor(s, 2);
        s += __shfl_xor(s, 4); s += __shfl_xor(s, 8);
        inv[j] = 1.f / fmaxf(sqrtf(s), 1e-12f);
      }
#pragma unroll
      for (int n = 0; n < 4; ++n)
#pragma unroll
        for (int j = 0; j < 4; ++j) vhp[m][n][j] = f2bf(val[n][j] * inv[j]);
    }
  }

  // ---- kv[i][j] += sum_s kh[s][i] vh[s][j], per head wc, 2 passes over s-halves ----
  // khT/vhT layout per head: [64 i][128 s] bf16, granule-swizzled: phys byte =
  // h*16384 + i*256 + ((s>>3)^(i&7))*16 + (s&7)*2. Reuses As (khT) and Bs (vhT).
  unsigned char* khT = (unsigned char*)&As[0][0][0];
  unsigned char* vhT = (unsigned char*)&Bs[0][0][0];
  f32x4 acc2[2][4];
#pragma unroll
  for (int mi = 0; mi < 2; ++mi)
#pragma unroll
    for (int nj = 0; nj < 4; ++nj) acc2[mi][nj] = (f32x4){0.f, 0.f, 0.f, 0.f};

#pragma unroll
  for (int p = 0; p < 2; ++p) {
    __syncthreads();
    if (wr == p) {
#pragma unroll
      for (int m = 0; m < 8; ++m)
#pragma unroll
        for (int n = 0; n < 4; ++n)
#pragma unroll
          for (int j = 0; j < 4; ++j) {
            const int s = m * 16 + g4 + j;  // local row in this half
            const int i = n * 16 + fr;
            const int off = wc * 16384 + i * 256 + (((s >> 3) ^ (i & 7)) * 16) + (s & 7) * 2;
            *(unsigned short*)(khT + off) = khp[m][n][j];
            *(unsigned short*)(vhT + off) = vhp[m][n][j];
          }
    }
    __syncthreads();
#pragma unroll
    for (int ks = 0; ks < 4; ++ks) {
      bf16x8 a2[2], b2[4];
#pragma unroll
      for (int mi = 0; mi < 2; ++mi) {
        const int i = wr * 32 + mi * 16 + fr;
        a2[mi] = *(const bf16x8*)(khT + wc * 16384 + i * 256 + (((ks * 4 + fkg) ^ (i & 7)) * 16));
      }
#pragma unroll
      for (int nj = 0; nj < 4; ++nj) {
        const int j = nj * 16 + fr;
        b2[nj] = *(const bf16x8*)(vhT + wc * 16384 + j * 256 + (((ks * 4 + fkg) ^ (j & 7)) * 16));
      }
#pragma unroll
      for (int mi = 0; mi < 2; ++mi)
#pragma unroll
        for (int nj = 0; nj < 4; ++nj)
          acc2[mi][nj] = __builtin_amdgcn_mfma_f32_16x16x32_bf16(a2[mi], b2[nj], acc2[mi][nj], 0, 0, 0);
    }
  }

  float* dst = kvp + ((size_t)(bm & 15) * 64 + (size_t)(bm >> 4) * 16 + bn * 4 + wc) * 4096;
#pragma unroll
  for (int mi = 0; mi < 2; ++mi)
#pragma unroll
    for (int nj = 0; nj < 4; ++nj)
#pragma unroll
      for (int jj = 0; jj < 4; ++jj)
        dst[(wr * 32 + mi * 16 + g4 + jj) * 64 + nj * 16 + fr] = acc2[mi][nj][jj];
}

// ---------------- final fold: out = (q@Wq^T + bq) @ kv per head (f32 out) ----------------
__global__ __launch_bounds__(512, 1) void final_fold_kernel(
    const unsigned short* __restrict__ A,    // q_bf [16384][1024]
    const unsigned short* __restrict__ Wqb,  // bf16 [1024][1024]
    const float* __restrict__ bq,            // [1024]
    const unsigned short* __restrict__ kvT,  // bf16 [4][16][64][64]  ([b][h][j][i])
    float* __restrict__ out) {
  __shared__ __align__(16) unsigned char smem[163840];
  unsigned short (*As)[256][32] = (unsigned short (*)[256][32])smem;
  unsigned short (*Bs)[256][32] = (unsigned short (*)[256][32])(smem + 65536);

  const int flat = blockIdx.y * 4 + blockIdx.x;  // 256, %8==0
  const int swz = (flat & 7) * 32 + (flat >> 3);
  const int bm = swz >> 2, bn = swz & 3;
  const int bB = bm >> 4;  // batch

  const int tid = threadIdx.x, widx = tid >> 6, lane = tid & 63;
  const int wr = widx >> 2, wc = widx & 3;
  const int fr = lane & 15, fkg = lane >> 4, g4 = fkg * 4;

  // stage kvT for this block's 4 heads into smem[131072..163839] (swizzled)
#pragma unroll
  for (int t = 0; t < 4; ++t) {
    int unit = t * 512 + tid;         // 0..2047
    int h = unit >> 9;                // 0..3
    int jr = (unit >> 3) & 63;        // j row
    int g = unit & 7;                 // 16B granule (8 per 128B row)
    ushort8 vvv = *(const ushort8*)(kvT +
        ((size_t)(bB * 16 + bn * 4 + h) * 4096) + jr * 64 + g * 8);
    *(ushort8*)(smem + 131072 + h * 8192 + jr * 128 + ((g ^ (jr & 7)) * 16)) = vvv;
  }
  __syncthreads();

  f32x4 acc[8][4];
#pragma unroll
  for (int m = 0; m < 8; ++m)
#pragma unroll
    for (int n = 0; n < 4; ++n) acc[m][n] = (f32x4){0.f, 0.f, 0.f, 0.f};

  gemm256_loop(A, Wqb, bm, bn, As, Bs, acc);

  // qp -> LDS: per-wave 16KB region [128 rows][64 i] bf16, granule-XOR swizzle
  {
    float bsv[4];
#pragma unroll
    for (int n = 0; n < 4; ++n) bsv[n] = bq[bn * 256 + wc * 64 + n * 16 + fr];
#pragma unroll
    for (int m = 0; m < 8; ++m)
#pragma unroll
      for (int n = 0; n < 4; ++n)
#pragma unroll
        for (int j = 0; j < 4; ++j) {
          float v = acc[m][n][j] + bsv[n];
          int r = m * 16 + g4 + j;   // local row 0..127
          int c = n * 16 + fr;       // local i 0..63
          *(unsigned short*)(smem + widx * 16384 + r * 128 +
                             (((c >> 3) ^ (r & 7)) * 16) + (c & 7) * 2) = f2bf(v);
        }
  }
  __syncthreads();

  // GEMM2: out_wave[128x64] = qp_wave[128x64] @ kv[head wc][64x64]
  f32x4 acc2[8][4];
#pragma unroll
  for (int m = 0; m < 8; ++m)
#pragma unroll
    for (int n = 0; n < 4; ++n) acc2[m][n] = (f32x4){0.f, 0.f, 0.f, 0.f};

#pragma unroll
  for (int ks = 0; ks < 2; ++ks) {
    bf16x8 a2[8], b2[4];
#pragma unroll
    for (int m = 0; m < 8; ++m)
      a2[m] = *(const bf16x8*)(smem + widx * 16384 + (m * 16 + fr) * 128 +
                               (((ks * 4 + fkg) ^ (fr & 7)) * 16));
#pragma unroll
    for (int n = 0; n < 4; ++n)
      b2[n] = *(const bf16x8*)(smem + 131072 + wc * 8192 + (n * 16 + fr) * 128 +
                               (((ks * 4 + fkg) ^ (fr & 7)) * 16));
#pragma unroll
    for (int m = 0; m < 8; ++m)
#pragma unroll
      for (int n = 0; n < 4; ++n)
        acc2[m][n] = __builtin_amdgcn_mfma_f32_16x16x32_bf16(a2[m], b2[n], acc2[m][n], 0, 0, 0);
  }

#pragma unroll
  for (int n = 0; n < 4; ++n) {
    const int col = bn * 256 + wc * 64 + n * 16 + fr;
#pragma unroll
    for (int m = 0; m < 8; ++m)
#pragma unroll
      for (int j = 0; j < 4; ++j) {
        const int row = bm * 256 + wr * 128 + m * 16 + g4 + j;
        out[(size_t)row * 1024 + col] = acc2[m][n][j];
      }
  }
}

// ============ kvT reduce: kvT[bh][j][i] = bf16( sum_c kvp[c][bh][i][j] ) ============
__global__ __launch_bounds__(256) void kvt_reduce_kernel(const float* __restrict__ kvp,
                                                         unsigned short* __restrict__ kvT) {
  const int bh = blockIdx.x;  // 0..63
  for (int e = threadIdx.x; e < 4096; e += 256) {
    float s = 0.f;
#pragma unroll
    for (int c = 0; c < 16; ++c) s += kvp[((size_t)c * 64 + bh) * 4096 + e];
    int i = e >> 6, j = e & 63;
    kvT[(size_t)bh * 4096 + j * 64 + i] = f2bf(s);
  }
}

extern "C" void kernel_launch(void* const* d_in, const int* in_sizes, int n_in,
                              void* d_out, int out_size, void* d_ws, size_t ws_size,
                              hipStream_t stream) {
  const float* q = (const float*)d_in[0];
  const float* k = (const float*)d_in[1];
  const float* v = (const float*)d_in[2];
  const float* Wq = (const float*)d_in[3];
  const float* bq = (const float*)d_in[4];
  const float* Wk = (const float*)d_in[5];
  const float* bk = (const float*)d_in[6];
  const float* Wv = (const float*)d_in[7];
  const float* bv = (const float*)d_in[8];
  float* out = (float*)d_out;

  const size_t NE = (size_t)16384 * 1024;
  const size_t MB = 1048576;

  char* ws = (char*)d_ws;
  unsigned short* kbf = (unsigned short*)(ws + 0 * MB);    // 32 MB
  unsigned short* vbf = (unsigned short*)(ws + 32 * MB);   // 32 MB
  unsigned short* qbf = (unsigned short*)(ws + 64 * MB);   // 32 MB
  float* kvp = (float*)(ws + 96 * MB);                     // 16 MB
  unsigned short* Wqb = (unsigned short*)(ws + 112 * MB);  // 2 MB
  unsigned short* Wkb = (unsigned short*)(ws + 114 * MB);  // 2 MB
  unsigned short* Wvb = (unsigned short*)(ws + 116 * MB);  // 2 MB
  unsigned short* kvT = (unsigned short*)(ws + 118 * MB);  // 512 KB

  // 1) q,k,v and weights -> bf16
  cvt3_kernel<<<dim3(8192, 3), 256, 0, stream>>>(q, k, v, qbf, kbf, vbf, (int)(NE / 8));
  cvt3_kernel<<<dim3(512, 3), 256, 0, stream>>>(Wq, Wk, Wv, Wqb, Wkb, Wvb, 131072);

  // 2) fused projections + norm + kv partials (kh/vh never touch HBM)
  projkv_kernel<<<dim3(4, 64), 512, 0, stream>>>(kbf, vbf, Wkb, Wvb, bk, bv, kvp);

  // 3) reduce partials -> kvT bf16 [b][h][j][i]
  kvt_reduce_kernel<<<64, 256, 0, stream>>>(kvp, kvT);

  // 4) out = (q@Wq^T + bq) @ kv  (folded, f32 out)
  final_fold_kernel<<<dim3(4, 64), 512, 0, stream>>>(qbf, Wqb, bq, kvT, out);
}

// Round 13
// 212.034 us; speedup vs baseline: 1.4174x; 1.4174x over previous
//
#include <hip/hip_runtime.h>
#include <hip/hip_bf16.h>
#include <stdint.h>

typedef __attribute__((ext_vector_type(8))) short bf16x8;
typedef __attribute__((ext_vector_type(4))) float f32x4;
typedef __attribute__((ext_vector_type(8))) unsigned short ushort8;

__device__ __forceinline__ float bf2f(unsigned short u) {
  union { unsigned int i; float f; } x; x.i = ((unsigned int)u) << 16; return x.f;
}
__device__ __forceinline__ unsigned short f2bf(float f) {
  union { __hip_bfloat16 h; unsigned short u; } x; x.h = __float2bfloat16(f); return x.u;
}

__device__ __forceinline__ void gload_lds16(const void* g, void* l) {
  __builtin_amdgcn_global_load_lds((__attribute__((address_space(1))) const void*)g,
                                   (__attribute__((address_space(3))) void*)l, 16, 0, 0);
}

// ---------------- f32 -> bf16 convert, 3 tensors batched on z ----------------
__global__ __launch_bounds__(256) void cvt3_kernel(const float* __restrict__ a,
                                                   const float* __restrict__ b,
                                                   const float* __restrict__ c,
                                                   unsigned short* __restrict__ oa,
                                                   unsigned short* __restrict__ ob,
                                                   unsigned short* __restrict__ oc,
                                                   int n8) {
  const float* in = blockIdx.y == 0 ? a : blockIdx.y == 1 ? b : c;
  unsigned short* out = blockIdx.y == 0 ? oa : blockIdx.y == 1 ? ob : oc;
  int i = blockIdx.x * 256 + threadIdx.x;
  if (i >= n8) return;
  const float4* p = (const float4*)(in + (size_t)i * 8);
  float4 x = p[0], y = p[1];
  ushort8 o;
  o[0] = f2bf(x.x); o[1] = f2bf(x.y); o[2] = f2bf(x.z); o[3] = f2bf(x.w);
  o[4] = f2bf(y.x); o[5] = f2bf(y.y); o[6] = f2bf(y.z); o[7] = f2bf(y.w);
  *(ushort8*)(out + (size_t)i * 8) = o;
}

// ======================================================================
// Shared 4-phase 256x256 GEMM K-loop. acc[8][4] += A[256,1024] @ B[256,1024]^T
// tile at (bm,bn). ONE barrier per phase: the pre-MFMA barrier is redundant —
// a wave's ds_reads are consumed at MFMA issue (lgkmcnt data-dep), so by its
// end-of-phase s_barrier all reads of any unit are complete; re-staging is
// ordered by the counted-vmcnt chain (each unit's loads verified complete
// >=1 phase before its consumer). Counted vmcnt(4) at P2/P4 only.
// Swizzle (0-conflict, r9-r11 verified): phys granule = logical ^ ((row>>1)&3).
// ======================================================================
__device__ __forceinline__ void gemm256_loop(
    const unsigned short* __restrict__ A,
    const unsigned short* __restrict__ B,
    int bm, int bn,
    unsigned short (*As)[256][32], unsigned short (*Bs)[256][32],
    f32x4 (*acc)[4]) {
  const int tid = threadIdx.x;
  const int widx = tid >> 6, lane = tid & 63;
  const int wr = widx >> 2, wc = widx & 3;
  const int fr = lane & 15, fkg = lane >> 4;
  const int pgo = (fkg ^ ((fr >> 1) & 3)) * 8;          // swizzled read granule
  const int srow = lane >> 2;                           // staging row-in-16
  const int sg = ((lane & 3) ^ ((lane >> 3) & 3)) * 8;  // swizzled source granule

  const size_t abase = (size_t)(bm * 256) * 1024;
  const size_t bbase = (size_t)(bn * 256) * 1024;

  bf16x8 aF[8], bF[4];

#define STG_A(bufi, kh, kt)                                                                \
  {                                                                                        \
    gload_lds16(A + abase + (size_t)(widx * 16 + srow) * 1024 + (kt) * 64 + (kh) * 32 + sg,\
                &As[(bufi) * 2 + (kh)][widx * 16][0]);                                     \
    gload_lds16(A + abase + (size_t)(128 + widx * 16 + srow) * 1024 + (kt) * 64 + (kh) * 32 + sg, \
                &As[(bufi) * 2 + (kh)][128 + widx * 16][0]);                               \
  }
#define STG_B(bufi, kh, kt)                                                                \
  {                                                                                        \
    gload_lds16(B + bbase + (size_t)(widx * 16 + srow) * 1024 + (kt) * 64 + (kh) * 32 + sg,\
                &Bs[(bufi) * 2 + (kh)][widx * 16][0]);                                     \
    gload_lds16(B + bbase + (size_t)(128 + widx * 16 + srow) * 1024 + (kt) * 64 + (kh) * 32 + sg, \
                &Bs[(bufi) * 2 + (kh)][128 + widx * 16][0]);                               \
  }
#define LDA(bufi, ks)                                                                      \
  _Pragma("unroll") for (int m = 0; m < 8; ++m)                                            \
      aF[m] = *(const bf16x8*)&As[(bufi) * 2 + (ks)][wr * 128 + m * 16 + fr][pgo];
#define LDBALL(bufi, ks)                                                                   \
  _Pragma("unroll") for (int n = 0; n < 4; ++n)                                            \
      bF[n] = *(const bf16x8*)&Bs[(bufi) * 2 + (ks)][wc * 64 + n * 16 + fr][pgo];
#define MMALL()                                                                            \
  {                                                                                        \
    __builtin_amdgcn_s_setprio(1);                                                         \
    _Pragma("unroll") for (int m = 0; m < 8; ++m)                                          \
        _Pragma("unroll") for (int n = 0; n < 4; ++n)                                      \
            acc[m][n] = __builtin_amdgcn_mfma_f32_16x16x32_bf16(aF[m], bF[n], acc[m][n], 0, 0, 0); \
    __builtin_amdgcn_s_setprio(0);                                                         \
  }
#define BARM() asm volatile("s_barrier" ::: "memory")
#define VMW(N) asm volatile("s_waitcnt vmcnt(" #N ")" ::: "memory")

  STG_A(0, 0, 0); STG_B(0, 0, 0);
  STG_A(0, 1, 0); STG_B(0, 1, 0);
  STG_A(1, 0, 1); STG_B(1, 0, 1);
  VMW(4);
  BARM();

  for (int i = 0; i < 8; ++i) {
    const int t1s = 2 * i + 1, u0 = 2 * i + 2, u1 = 2 * i + 3;
    const bool st = (i < 7);
    // P1: compute (b0,k0); stage (b1,k1) <- tile t1s
    LDA(0, 0); LDBALL(0, 0); STG_A(1, 1, t1s); STG_B(1, 1, t1s);
    MMALL(); BARM();
    // P2: compute (b0,k1); stage (b0,k0) <- u0 ; counted wait
    LDA(0, 1); LDBALL(0, 1); if (st) { STG_A(0, 0, u0); STG_B(0, 0, u0); }
    MMALL();
    if (st) { VMW(4); } else { VMW(0); }
    BARM();
    // P3: compute (b1,k0); stage (b0,k1) <- u0
    LDA(1, 0); LDBALL(1, 0); if (st) { STG_A(0, 1, u0); STG_B(0, 1, u0); }
    MMALL(); BARM();
    // P4: compute (b1,k1); stage (b1,k0) <- u1 ; counted wait
    LDA(1, 1); LDBALL(1, 1); if (st) { STG_A(1, 0, u1); STG_B(1, 0, u1); }
    MMALL();
    if (st) { VMW(4); } else { VMW(0); }
    BARM();
  }
#undef STG_A
#undef STG_B
#undef LDA
#undef LDBALL
#undef MMALL
#undef BARM
#undef VMW
}

// ---------------- proj pair: kh = norm(k@Wk^T+bk), vh = norm(v@Wv^T+bv) ----------------
__global__ __launch_bounds__(512, 1) void proj_norm_kernel(
    const unsigned short* __restrict__ A0, const unsigned short* __restrict__ A1,
    const unsigned short* __restrict__ B0, const unsigned short* __restrict__ B1,
    const float* __restrict__ bias0, const float* __restrict__ bias1,
    unsigned short* __restrict__ C0, unsigned short* __restrict__ C1) {
  __shared__ unsigned short As[4][256][32];
  __shared__ unsigned short Bs[4][256][32];
  const int flat = (blockIdx.z * 64 + blockIdx.y) * 4 + blockIdx.x;  // 512, %8==0
  const int swz = (flat & 7) * 64 + (flat >> 3);                     // bijective
  const int zz = swz >> 8;
  const int rem = swz & 255;
  const int bm = rem >> 2, bn = rem & 3;
  const unsigned short* A = zz ? A1 : A0;
  const unsigned short* B = zz ? B1 : B0;
  const float* bias = zz ? bias1 : bias0;
  unsigned short* C = zz ? C1 : C0;

  f32x4 acc[8][4];
#pragma unroll
  for (int m = 0; m < 8; ++m)
#pragma unroll
    for (int n = 0; n < 4; ++n) acc[m][n] = (f32x4){0.f, 0.f, 0.f, 0.f};

  gemm256_loop(A, B, bm, bn, As, Bs, acc);

  const int tid = threadIdx.x, widx = tid >> 6, lane = tid & 63;
  const int wr = widx >> 2, wc = widx & 3;
  const int fr = lane & 15, g4 = (lane >> 4) * 4;

  float bsv[4];
#pragma unroll
  for (int n = 0; n < 4; ++n) bsv[n] = bias[bn * 256 + wc * 64 + n * 16 + fr];
#pragma unroll
  for (int m = 0; m < 8; ++m) {
    float val[4][4];  // [n][j]
    float inv[4];
#pragma unroll
    for (int j = 0; j < 4; ++j) {
      float s = 0.f;
#pragma unroll
      for (int n = 0; n < 4; ++n) {
        val[n][j] = acc[m][n][j] + bsv[n];
        s += val[n][j] * val[n][j];
      }
      s += __shfl_xor(s, 1); s += __shfl_xor(s, 2);
      s += __shfl_xor(s, 4); s += __shfl_xor(s, 8);
      inv[j] = 1.f / fmaxf(sqrtf(s), 1e-12f);
    }
#pragma unroll
    for (int n = 0; n < 4; ++n) {
      const int col = bn * 256 + wc * 64 + n * 16 + fr;
#pragma unroll
      for (int j = 0; j < 4; ++j) {
        const int row = bm * 256 + wr * 128 + m * 16 + g4 + j;
        C[(size_t)row * 1024 + col] = f2bf(val[n][j] * inv[j]);
      }
    }
  }
}

// ---------------- final fold: out = (q@Wq^T + bq) @ kv per head (f32 out) ----------------
__global__ __launch_bounds__(512, 1) void final_fold_kernel(
    const unsigned short* __restrict__ A,    // q_bf [16384][1024]
    const unsigned short* __restrict__ Wqb,  // bf16 [1024][1024]
    const float* __restrict__ bq,            // [1024]
    const unsigned short* __restrict__ kvT,  // bf16 [4][16][64][64]  ([b][h][j][i])
    float* __restrict__ out) {
  __shared__ __align__(16) unsigned char smem[163840];
  unsigned short (*As)[256][32] = (unsigned short (*)[256][32])smem;
  unsigned short (*Bs)[256][32] = (unsigned short (*)[256][32])(smem + 65536);

  const int flat = blockIdx.y * 4 + blockIdx.x;  // 256, %8==0
  const int swz = (flat & 7) * 32 + (flat >> 3);
  const int bm = swz >> 2, bn = swz & 3;
  const int bB = bm >> 4;  // batch

  const int tid = threadIdx.x, widx = tid >> 6, lane = tid & 63;
  const int wr = widx >> 2, wc = widx & 3;
  const int fr = lane & 15, fkg = lane >> 4, g4 = fkg * 4;

  // stage kvT for this block's 4 heads into smem[131072..163839] (swizzled)
#pragma unroll
  for (int t = 0; t < 4; ++t) {
    int unit = t * 512 + tid;         // 0..2047
    int h = unit >> 9;                // 0..3
    int jr = (unit >> 3) & 63;        // j row
    int g = unit & 7;                 // 16B granule (8 per 128B row)
    ushort8 vvv = *(const ushort8*)(kvT +
        ((size_t)(bB * 16 + bn * 4 + h) * 4096) + jr * 64 + g * 8);
    *(ushort8*)(smem + 131072 + h * 8192 + jr * 128 + ((g ^ (jr & 7)) * 16)) = vvv;
  }
  __syncthreads();

  f32x4 acc[8][4];
#pragma unroll
  for (int m = 0; m < 8; ++m)
#pragma unroll
    for (int n = 0; n < 4; ++n) acc[m][n] = (f32x4){0.f, 0.f, 0.f, 0.f};

  gemm256_loop(A, Wqb, bm, bn, As, Bs, acc);

  // qp -> LDS: per-wave 16KB region [128 rows][64 i] bf16, granule-XOR swizzle
  {
    float bsv[4];
#pragma unroll
    for (int n = 0; n < 4; ++n) bsv[n] = bq[bn * 256 + wc * 64 + n * 16 + fr];
#pragma unroll
    for (int m = 0; m < 8; ++m)
#pragma unroll
      for (int n = 0; n < 4; ++n)
#pragma unroll
        for (int j = 0; j < 4; ++j) {
          float v = acc[m][n][j] + bsv[n];
          int r = m * 16 + g4 + j;   // local row 0..127
          int c = n * 16 + fr;       // local i 0..63
          *(unsigned short*)(smem + widx * 16384 + r * 128 +
                             (((c >> 3) ^ (r & 7)) * 16) + (c & 7) * 2) = f2bf(v);
        }
  }
  __syncthreads();

  // GEMM2: out_wave[128x64] = qp_wave[128x64] @ kv[head wc][64x64]
  f32x4 acc2[8][4];
#pragma unroll
  for (int m = 0; m < 8; ++m)
#pragma unroll
    for (int n = 0; n < 4; ++n) acc2[m][n] = (f32x4){0.f, 0.f, 0.f, 0.f};

#pragma unroll
  for (int ks = 0; ks < 2; ++ks) {
    bf16x8 a2[8], b2[4];
#pragma unroll
    for (int m = 0; m < 8; ++m)
      a2[m] = *(const bf16x8*)(smem + widx * 16384 + (m * 16 + fr) * 128 +
                               (((ks * 4 + fkg) ^ (fr & 7)) * 16));
#pragma unroll
    for (int n = 0; n < 4; ++n)
      b2[n] = *(const bf16x8*)(smem + 131072 + wc * 8192 + (n * 16 + fr) * 128 +
                               (((ks * 4 + fkg) ^ (fr & 7)) * 16));
#pragma unroll
    for (int m = 0; m < 8; ++m)
#pragma unroll
      for (int n = 0; n < 4; ++n)
        acc2[m][n] = __builtin_amdgcn_mfma_f32_16x16x32_bf16(a2[m], b2[n], acc2[m][n], 0, 0, 0);
  }

#pragma unroll
  for (int n = 0; n < 4; ++n) {
    const int col = bn * 256 + wc * 64 + n * 16 + fr;
#pragma unroll
    for (int m = 0; m < 8; ++m)
#pragma unroll
      for (int j = 0; j < 4; ++j) {
        const int row = bm * 256 + wr * 128 + m * 16 + g4 + j;
        out[(size_t)row * 1024 + col] = acc2[m][n][j];
      }
  }
}

// ============ kv partials: kvp[chunk][b*16+h][i][j] = sum_{s in chunk} kh[s][i]*vh[s][j] ============
__global__ __launch_bounds__(256) void kv_part_kernel(const unsigned short* __restrict__ kh,
                                                      const unsigned short* __restrict__ vh,
                                                      float* __restrict__ kvp) {
  const int chunk = blockIdx.x, h = blockIdx.y, b = blockIdx.z;
  __shared__ unsigned short khT[64][264];
  __shared__ unsigned short vhT[64][264];
  const int tid = threadIdx.x, wid = tid >> 6, lane = tid & 63;
  const int fr = lane & 15, fk = (lane >> 4) * 8, g4 = (lane >> 4) * 4;

  const int jb = tid & 7, sb = tid >> 3;
  const size_t base = ((size_t)b * 4096 + chunk * 256) * 1024 + h * 64;
  {
    ushort8 rk[8], rv[8];
#pragma unroll
    for (int u = 0; u < 8; ++u) {
      rk[u] = *(const ushort8*)(kh + base + (size_t)(sb * 8 + u) * 1024 + jb * 8);
      rv[u] = *(const ushort8*)(vh + base + (size_t)(sb * 8 + u) * 1024 + jb * 8);
    }
#pragma unroll
    for (int jj = 0; jj < 8; ++jj) {
      ushort8 ck, cv;
#pragma unroll
      for (int u = 0; u < 8; ++u) { ck[u] = rk[u][jj]; cv[u] = rv[u][jj]; }
      *(ushort8*)&khT[jb * 8 + jj][sb * 8] = ck;
      *(ushort8*)&vhT[jb * 8 + jj][sb * 8] = cv;
    }
  }
  __syncthreads();

  f32x4 acc2[4];
#pragma unroll
  for (int n = 0; n < 4; ++n) acc2[n] = (f32x4){0.f, 0.f, 0.f, 0.f};
#pragma unroll
  for (int ks = 0; ks < 8; ++ks) {
    bf16x8 a2 = *(const bf16x8*)&khT[wid * 16 + fr][ks * 32 + fk];
    bf16x8 b2[4];
#pragma unroll
    for (int jt = 0; jt < 4; ++jt) b2[jt] = *(const bf16x8*)&vhT[jt * 16 + fr][ks * 32 + fk];
#pragma unroll
    for (int jt = 0; jt < 4; ++jt)
      acc2[jt] = __builtin_amdgcn_mfma_f32_16x16x32_bf16(a2, b2[jt], acc2[jt], 0, 0, 0);
  }
  float* dst = kvp + ((size_t)chunk * 64 + b * 16 + h) * 4096;
#pragma unroll
  for (int jt = 0; jt < 4; ++jt)
#pragma unroll
    for (int jj = 0; jj < 4; ++jj)
      dst[(wid * 16 + g4 + jj) * 64 + jt * 16 + fr] = acc2[jt][jj];
}

// ============ kvT reduce: kvT[bh][j][i] = bf16( sum_c kvp[c][bh][i][j] ) ============
__global__ __launch_bounds__(256) void kvt_reduce_kernel(const float* __restrict__ kvp,
                                                         unsigned short* __restrict__ kvT) {
  const int bh = blockIdx.x;  // 0..63
  for (int e = threadIdx.x; e < 4096; e += 256) {
    float s = 0.f;
#pragma unroll
    for (int c = 0; c < 16; ++c) s += kvp[((size_t)c * 64 + bh) * 4096 + e];
    int i = e >> 6, j = e & 63;
    kvT[(size_t)bh * 4096 + j * 64 + i] = f2bf(s);
  }
}

extern "C" void kernel_launch(void* const* d_in, const int* in_sizes, int n_in,
                              void* d_out, int out_size, void* d_ws, size_t ws_size,
                              hipStream_t stream) {
  const float* q = (const float*)d_in[0];
  const float* k = (const float*)d_in[1];
  const float* v = (const float*)d_in[2];
  const float* Wq = (const float*)d_in[3];
  const float* bq = (const float*)d_in[4];
  const float* Wk = (const float*)d_in[5];
  const float* bk = (const float*)d_in[6];
  const float* Wv = (const float*)d_in[7];
  const float* bv = (const float*)d_in[8];
  float* out = (float*)d_out;

  const size_t NE = (size_t)16384 * 1024;
  const size_t MB = 1048576;

  char* ws = (char*)d_ws;
  unsigned short* kbf = (unsigned short*)(ws + 0 * MB);    // 32 MB; later kvp (16 MB)
  unsigned short* qbf = (unsigned short*)(ws + 32 * MB);   // 32 MB
  unsigned short* kh = (unsigned short*)(ws + 64 * MB);    // 32 MB
  unsigned short* vh = (unsigned short*)(ws + 96 * MB);    // 32 MB
  unsigned short* vbf = (unsigned short*)(ws + 64 * MB);   // aliases kh slot pre-proj? NO — see below
  unsigned short* Wqb = (unsigned short*)(ws + 128 * MB);  // 2 MB
  unsigned short* Wkb = (unsigned short*)(ws + 130 * MB);  // 2 MB
  unsigned short* Wvb = (unsigned short*)(ws + 132 * MB);  // 2 MB
  unsigned short* kvT = (unsigned short*)(ws + 134 * MB);  // 512 KB
  float* kvp = (float*)kbf;                                // 16 MB (kbf dead after proj)

  // vbf must not alias kh/vh (proj writes kh/vh while reading vbf).
  // Layout: kbf@0, qbf@32, vbf needs its own slot -> use 134.5MB.. no: place
  // vbf in the kvT-adjacent region is too small. Real layout:
  //   kbf @ 0, vbf @ 32, qbf @ 64 is wrong (qbf needed after proj)...
  // Simplest correct: kbf@0, vbf@32, qbf@64, kh@96... exceeds? 96+32+32(vh)=160+6+0.5
  // ws proved >=151MB in r1? r1 used 135MB. Keep within 135MB:
  //   kbf@0 (dies after proj) ; vbf@32 (dies after proj) ; qbf@64 (lives) ;
  //   kh@96 ; vh -> reuse kbf slot? kh/vh written DURING proj while kbf/vbf read. NO.
  // Use: kh@96, vh@0..? vh written while vbf READ: vh can overwrite kbf? kbf is
  // read during proj (A of k-GEMM) -> cannot. Solution: proj z-order: all reads
  // kbf/vbf, writes kh/vh must be disjoint: slots kbf@0, vbf@32, qbf@64, kh@96,
  // vh@... need 5th slot: total 160MB+6+0.5. r1 passed with 135MB; 167MB may
  // exceed ws. Fall back to r11's proven trick: convert q AFTER proj into the
  // then-dead vbf slot. So: cvt3 converts only k,v (+weights separately), and
  // q is converted post-proj. This keeps r11's exact 134.5MB footprint.
  (void)vbf;

  unsigned short* kbf_ = (unsigned short*)(ws + 0 * MB);   // k_bf; later kvp
  unsigned short* vbf_ = (unsigned short*)(ws + 32 * MB);  // v_bf; later q_bf
  unsigned short* qbf_ = vbf_;                             // q_bf after proj

  // 1) k,v -> bf16 (z=2 via cvt3 with c duplicated-safe: use separate grids)
  cvt3_kernel<<<dim3(8192, 2), 256, 0, stream>>>(k, v, v, kbf_, vbf_, vbf_, (int)(NE / 8));
  cvt3_kernel<<<dim3(512, 3), 256, 0, stream>>>(Wq, Wk, Wv, Wqb, Wkb, Wvb, 131072);

  // 2) projections + bias + L2 norm (256^2 4-phase, single barrier/phase)
  proj_norm_kernel<<<dim3(4, 64, 2), 512, 0, stream>>>(kbf_, vbf_, Wkb, Wvb, bk, bv, kh, vh);

  // 3) q -> bf16 (into v_bf slot, now dead)
  cvt3_kernel<<<dim3(8192, 1), 256, 0, stream>>>(q, q, q, qbf_, qbf_, qbf_, (int)(NE / 8));

  // 4) kv chunk partials (deterministic, into k_bf slot, now dead)
  kv_part_kernel<<<dim3(16, 16, 4), 256, 0, stream>>>(kh, vh, kvp);

  // 5) reduce partials -> kvT bf16 [b][h][j][i]
  kvt_reduce_kernel<<<64, 256, 0, stream>>>(kvp, kvT);

  // 6) out = (q@Wq^T + bq) @ kv  (folded, f32 out)
  final_fold_kernel<<<dim3(4, 64), 512, 0, stream>>>(qbf_, Wqb, bq, kvT, out);
}